// Round 13
// baseline (355.017 us; speedup 1.0000x reference)
//
#include <hip/hip_runtime.h>
#include <stdint.h>

#define NN 50000
#define NE 800000
#define HID 128
#define NG 64
#define BN_EPS 1e-5f
#define SC_NB 8                                  // buckets (== XCD count)
#define SC_BSZ ((NN + SC_NB - 1) / SC_NB)        // 6250 nodes per bucket
#define SC_CHUNK 4096                            // edges per block
#define SC_CHUNKS ((NE + SC_CHUNK - 1) / SC_CHUNK)
#define CAP 96          // fixed CSR row capacity; Poisson(16) P(deg>96) ~ 1e-40
#define LAYER_BLOCKS (NN / 16)                   // 3125 blocks x 16 nodes (exact)
#define NPART 64        // BN-stat partial slots (block & 63); kills atomic contention

typedef __bf16 bf16x8 __attribute__((ext_vector_type(8)));
typedef float floatx4 __attribute__((ext_vector_type(4)));

__device__ __forceinline__ float b2f(unsigned short u) {
    union { unsigned int i; float f; } x; x.i = ((unsigned int)u) << 16; return x.f;
}
__device__ __forceinline__ float blo(unsigned int d) { return __uint_as_float(d << 16); }
__device__ __forceinline__ float bhi(unsigned int d) { return __uint_as_float(d & 0xffff0000u); }
__device__ __forceinline__ unsigned short f2b(float f) {
    union { float f; unsigned int i; } x; x.f = f; unsigned int i = x.i;
    if ((i & 0x7f800000u) == 0x7f800000u) return (unsigned short)(i >> 16); // inf/nan
    return (unsigned short)((i + 0x7fffu + ((i >> 16) & 1u)) >> 16);        // RNE
}
__device__ __forceinline__ unsigned int pack2(float f0, float f1) {
    return (((unsigned int)f2b(f1)) << 16) | f2b(f0);
}
// folded BN scale/shift for column c from the 64-slot partial-sum array
__device__ __forceinline__ float2 bn_pair_part(const float* __restrict__ part,
                                               const float* __restrict__ gamma,
                                               const float* __restrict__ beta, int c) {
    float s = 0.f, sq = 0.f;
#pragma unroll 8
    for (int k = 0; k < NPART; ++k) {
        s += part[k * 256 + c];
        sq += part[k * 256 + 128 + c];
    }
    float mu = s * (1.f / NN);
    float var = sq * (1.f / NN) - mu * mu;
    float sc = gamma[c] * rsqrtf(var + BN_EPS);
    return make_float2(sc, beta[c] - mu * sc);
}
// first index i with batch[i] >= val (batch sorted ascending)
__device__ __forceinline__ int lbound(const int* __restrict__ batch, int val) {
    int lo = 0, hi = NN;
    while (lo < hi) { int mid = (lo + hi) >> 1; if (batch[mid] < val) lo = mid + 1; else hi = mid; }
    return lo;
}

// ---------------- setup (incl. weight prep) ----------------
__global__ void k_setup(const float* __restrict__ x, unsigned short* xb, int* cnt,
                        float* part, float* pool_sum, int* pool_max,
                        const float* __restrict__ Wl0, const float* __restrict__ Wr0,
                        const float* __restrict__ Wl1, const float* __restrict__ Wr1,
                        const float* __restrict__ Wl2, const float* __restrict__ Wr2,
                        unsigned short* Bp) {
    int i = blockIdx.x * 256 + threadIdx.x;
    if (i < NN * 64) {
        float2 v = ((const float2*)x)[i];
        ((unsigned int*)xb)[i] = pack2(v.x, v.y);
    }
    if (i < NN) cnt[i] = 0;
    if (i < 3 * NPART * 256) part[i] = 0.f;
    if (i < NG * HID) { pool_sum[i] = 0.f; pool_max[i] = 0; }
    if (i < 3 * 32768) {
        int layer = i >> 15;
        int r = i & 32767;
        int nt = r >> 12, kk = (r >> 9) & 7, l = (r >> 3) & 63, j = r & 7;
        int k = kk * 32 + (l >> 4) * 8 + j;
        int n = nt * 16 + (l & 15);
        const float* Wl = layer == 0 ? Wl0 : (layer == 1 ? Wl1 : Wl2);
        const float* Wr = layer == 0 ? Wr0 : (layer == 1 ? Wr1 : Wr2);
        Bp[i] = f2b((k < 128) ? Wl[k * 128 + n] : Wr[(k - 128) * 128 + n]);
    }
}

// XCD-bucketized scatter into fixed-capacity CSR (no hist/scan needed)
__global__ void k_scatter(const int* __restrict__ src, const int* __restrict__ dst,
                          int* cnt, int* col) {
    int bucket = blockIdx.x & (SC_NB - 1);
    int chunk = blockIdx.x / SC_NB;
    int lo = bucket * SC_BSZ, hi = lo + SC_BSZ;
    int base = chunk * SC_CHUNK;
#pragma unroll
    for (int i = 0; i < SC_CHUNK / 256; ++i) {
        int e = base + i * 256 + threadIdx.x;
        if (e < NE) {
            int d = dst[e];
            if (d >= lo && d < hi) {
                int p = atomicAdd(&cnt[d], 1);
                if (p < CAP) col[d * CAP + p] = src[e];
            }
        }
    }
}

// ---------------- fused layer: [norm+] gather-agg (LDS) + GEMM + BN partials -
// 16 nodes/block, 3125 blocks. AP=1 folds the previous layer's BN+relu into
// the gather per-edge (R6-proven arithmetic): block builds 128 scale/shift
// pairs from the part array (64KB L2-hot), each lane keeps its 8 columns in
// registers, neighbor AND self values transformed in phase 1. Kills the
// separate k_norm dispatch (+gap, ~14us each). Phase 2 (MFMA; A from
// XOR-swizzled LDS, B from L2) is AP-independent. Stats -> part[b&63][256].
template <int AP>
__global__ void __launch_bounds__(256) k_layer(const unsigned short* __restrict__ h,
                                               const int* __restrict__ cnt,
                                               const int* __restrict__ col,
                                               const unsigned short* __restrict__ Bg,
                                               const float* __restrict__ pbpart,
                                               const float* __restrict__ pgamma,
                                               const float* __restrict__ pbeta,
                                               float* __restrict__ part,
                                               unsigned short* __restrict__ out) {
    __shared__ uint4 aggt4[256];   // 4KB agg fragments (swizzled)
    __shared__ uint4 selft4[256];  // 4KB self-term fragments (swizzled)
    __shared__ float s_sc[128], s_sh[128];
    int t = threadIdx.x;
    int wid = t >> 6, lane = t & 63;
    if (AP) {
        if (t < 128) {
            float2 p = bn_pair_part(pbpart, pgamma, pbeta, t);
            s_sc[t] = p.x; s_sh[t] = p.y;
        }
        __syncthreads();
    }
    const uint4* h4 = (const uint4*)h;  // one row = 16 uint4 (256B)
    // ---- phase 1: gather (16 lanes/node, 4 nodes/wave, 16 nodes/block) ----
    {
        int slot = lane >> 4, sub = lane & 15;
        int nl = wid * 4 + slot;                 // node_local in [0,16)
        int node = blockIdx.x * 16 + nl;         // always < NN (3125*16 == NN)
        int n = cnt[node]; if (n > CAP) n = CAP;
        const int* row = col + (size_t)node * CAP;
        float scv[8], shv[8];
        if (AP) {
#pragma unroll
            for (int i = 0; i < 8; ++i) {
                scv[i] = s_sc[sub * 8 + i];
                shv[i] = s_sh[sub * 8 + i];
            }
        }
        auto tf = [&](float f, int i) -> float {
            return AP ? fmaxf(f * scv[i] + shv[i], 0.f) : f;
        };
        float a0 = 0.f, a1 = 0.f, a2 = 0.f, a3 = 0.f, a4 = 0.f, a5 = 0.f, a6 = 0.f, a7 = 0.f;
        auto acc16 = [&](uint4 v) {
            a0 += tf(blo(v.x), 0);  a1 += tf(bhi(v.x), 1);
            a2 += tf(blo(v.y), 2);  a3 += tf(bhi(v.y), 3);
            a4 += tf(blo(v.z), 4);  a5 += tf(bhi(v.z), 5);
            a6 += tf(blo(v.w), 6);  a7 += tf(bhi(v.w), 7);
        };
        int j = 0;
        for (; j + 8 <= n; j += 8) {
            int us[8];
            uint4 vs[8];
#pragma unroll
            for (int uu = 0; uu < 8; ++uu) us[uu] = row[j + uu];
#pragma unroll
            for (int uu = 0; uu < 8; ++uu) vs[uu] = h4[(size_t)us[uu] * 16 + sub];
#pragma unroll
            for (int uu = 0; uu < 8; ++uu) acc16(vs[uu]);
        }
        for (; j + 4 <= n; j += 4) {
            int us[4];
            uint4 vs[4];
#pragma unroll
            for (int uu = 0; uu < 4; ++uu) us[uu] = row[j + uu];
#pragma unroll
            for (int uu = 0; uu < 4; ++uu) vs[uu] = h4[(size_t)us[uu] * 16 + sub];
#pragma unroll
            for (int uu = 0; uu < 4; ++uu) acc16(vs[uu]);
        }
        for (; j < n; ++j) {
            acc16(h4[(size_t)row[j] * 16 + sub]);
        }
        float inv = (n > 0) ? 1.f / (float)n : 0.f;
        uint4 o;
        o.x = pack2(a0 * inv, a1 * inv);
        o.y = pack2(a2 * inv, a3 * inv);
        o.z = pack2(a4 * inv, a5 * inv);
        o.w = pack2(a6 * inv, a7 * inv);
        int swz = sub ^ (nl & 7);                // XOR-swizzle 16B chunks
        aggt4[nl * 16 + swz] = o;
        // self-term row, transformed at store time (same scv/shv columns)
        uint4 sv = h4[(size_t)node * 16 + sub];
        uint4 so;
        so.x = pack2(tf(blo(sv.x), 0), tf(bhi(sv.x), 1));
        so.y = pack2(tf(blo(sv.y), 2), tf(bhi(sv.y), 3));
        so.z = pack2(tf(blo(sv.z), 4), tf(bhi(sv.z), 5));
        so.w = pack2(tf(blo(sv.w), 6), tf(bhi(sv.w), 7));
        selft4[nl * 16 + swz] = so;
    }
    __syncthreads();
    // ---- phase 2: MFMA; wave wid handles N-tiles nt = 2*wid, 2*wid+1 ----
    int m = lane & 15, q = lane >> 4;
    int mbase = blockIdx.x * 16;
    const bf16x8* Bv = (const bf16x8*)Bg;
    bf16x8 af[8];
#pragma unroll
    for (int kk = 0; kk < 4; ++kk) {
        int ci = (kk * 4 + q) ^ (m & 7);
        af[kk] = *(const bf16x8*)&aggt4[m * 16 + ci];
        af[4 + kk] = *(const bf16x8*)&selft4[m * 16 + ci];
    }
    floatx4 acc[2];
    acc[0] = (floatx4){0.f, 0.f, 0.f, 0.f};
    acc[1] = (floatx4){0.f, 0.f, 0.f, 0.f};
#pragma unroll
    for (int kk = 0; kk < 8; ++kk) {
#pragma unroll
        for (int ntl = 0; ntl < 2; ++ntl) {
            int nt = wid * 2 + ntl;
            bf16x8 b = Bv[(nt * 8 + kk) * 64 + lane];  // L2-resident broadcast
            acc[ntl] = __builtin_amdgcn_mfma_f32_16x16x32_bf16(af[kk], b, acc[ntl], 0, 0, 0);
        }
    }
    float s8[2] = {0.f, 0.f}, ss8[2] = {0.f, 0.f};
#pragma unroll
    for (int ntl = 0; ntl < 2; ++ntl) {
        int c = (wid * 2 + ntl) * 16 + m;  // C/D: col = lane&15
#pragma unroll
        for (int reg = 0; reg < 4; ++reg) {
            int r = mbase + q * 4 + reg;   // C/D: row = quad*4+reg; always < NN
            float v = acc[ntl][reg];
            out[(size_t)r * 128 + c] = f2b(v);
            s8[ntl] += v;
            ss8[ntl] += v * v;
        }
        s8[ntl] += __shfl_xor(s8[ntl], 16, 64);  s8[ntl] += __shfl_xor(s8[ntl], 32, 64);
        ss8[ntl] += __shfl_xor(ss8[ntl], 16, 64); ss8[ntl] += __shfl_xor(ss8[ntl], 32, 64);
    }
    float* pb = part + (blockIdx.x & (NPART - 1)) * 256;
    if (lane < 16) {
#pragma unroll
        for (int ntl = 0; ntl < 2; ++ntl) {
            int c = (wid * 2 + ntl) * 16 + m;
            atomicAdd(&pb[c], s8[ntl]);
            atomicAdd(&pb[128 + c], ss8[ntl]);
        }
    }
}

// ---------------- pooling (folded norm inline; bounds via binary search) -----
__global__ void k_pool(const unsigned short* __restrict__ h, const int* __restrict__ batch,
                       const float* __restrict__ part,
                       const float* __restrict__ gamma, const float* __restrict__ beta,
                       float* pool_sum, int* pool_max) {
    int g = blockIdx.x >> 3, chunk = blockIdx.x & 7;
    int s = lbound(batch, g), e1 = lbound(batch, g + 1);
    if (s >= e1) return;
    int cnt = e1 - s;
    int per = (cnt + 7) >> 3;
    int r0 = s + chunk * per;
    int r1 = min(r0 + per, e1);
    int c = threadIdx.x & 127, half = threadIdx.x >> 7;
    float2 pr = bn_pair_part(part, gamma, beta, c);
    float sm = 0.f, mx = 0.f;  // post-relu values are >= 0
    for (int r = r0 + half; r < r1; r += 2) {
        float v = fmaxf(b2f(h[(size_t)r * 128 + c]) * pr.x + pr.y, 0.f);
        sm += v;
        mx = fmaxf(mx, v);
    }
    atomicAdd(&pool_sum[g * 128 + c], sm);
    atomicMax(&pool_max[g * 128 + c], __float_as_int(mx));  // valid for >=0 floats
}

__global__ void __launch_bounds__(128) k_head(
    const float* __restrict__ pool_sum, const int* __restrict__ pool_max,
    const int* __restrict__ batch, const float* __restrict__ gfeats,
    const float* __restrict__ W1, const float* __restrict__ bs1,
    const float* __restrict__ W2, const float* __restrict__ bs2,
    const float* __restrict__ W3, const float* __restrict__ bs3,
    float* out) {
    __shared__ float m[288];
    __shared__ float o1[128];
    __shared__ float o2[64];
    int g = blockIdx.x, t = threadIdx.x;
    int cint = lbound(batch, g + 1) - lbound(batch, g);
    float cnt = (float)(cint < 1 ? 1 : cint);
    if (t < 128) {
        m[t] = pool_sum[g * 128 + t] / cnt;
        m[128 + t] = __int_as_float(pool_max[g * 128 + t]);
    }
    if (t < 32) m[256 + t] = gfeats[g * 32 + t];
    __syncthreads();
    float acc = bs1[t];
    for (int k = 0; k < 288; ++k) acc += m[k] * W1[k * 128 + t];
    o1[t] = fmaxf(acc, 0.f);
    __syncthreads();
    if (t < 64) {
        float a2 = bs2[t];
        for (int k = 0; k < 128; ++k) a2 += o1[k] * W2[k * 64 + t];
        o2[t] = fmaxf(a2, 0.f);
    }
    __syncthreads();
    if (t < 64) {
        float p = o2[t] * W3[t];
#pragma unroll
        for (int off = 32; off; off >>= 1) p += __shfl_down(p, off, 64);
        if (t == 0) out[g] = p + bs3[0];
    }
}

// ---------------- launch ----------------
extern "C" void kernel_launch(void* const* d_in, const int* in_sizes, int n_in,
                              void* d_out, int out_size, void* d_ws, size_t ws_size,
                              hipStream_t stream) {
    const float* x = (const float*)d_in[0];
    const int* ei = (const int*)d_in[1];
    const int* batch = (const int*)d_in[2];
    const float* gfeats = (const float*)d_in[3];
    const float *Wl[3], *Wr[3], *gma[3], *bta[3];
    for (int i = 0; i < 3; ++i) {
        Wl[i] = (const float*)d_in[4 + 5 * i];
        // d_in[5+5i] = bl (cancelled by BatchNorm; unused)
        Wr[i] = (const float*)d_in[6 + 5 * i];
        gma[i] = (const float*)d_in[7 + 5 * i];
        bta[i] = (const float*)d_in[8 + 5 * i];
    }
    const float* W1 = (const float*)d_in[19];
    const float* bs1 = (const float*)d_in[20];
    const float* W2 = (const float*)d_in[21];
    const float* bs2 = (const float*)d_in[22];
    const float* W3 = (const float*)d_in[23];
    const float* bs3 = (const float*)d_in[24];

    char* p = (char*)d_ws;
    auto alloc = [&](size_t bytes) -> char* {
        char* r = p;
        p += (bytes + 255) & ~(size_t)255;
        return r;
    };
    int* cnt = (int*)alloc(NN * 4);
    int* col = (int*)alloc((size_t)NN * CAP * 4);
    float* part = (float*)alloc(3 * NPART * 256 * 4);  // BN partial sums
    float* pool_sum = (float*)alloc(NG * HID * 4);
    int* pool_max = (int*)alloc(NG * HID * 4);
    unsigned short* Bp = (unsigned short*)alloc(3 * 32768 * 2);
    unsigned short* xb = (unsigned short*)alloc((size_t)NN * 128 * 2);
    unsigned short* b0 = (unsigned short*)alloc((size_t)NN * 128 * 2);
    unsigned short* b1 = (unsigned short*)alloc((size_t)NN * 128 * 2);

    const int* srcv = ei;
    const int* dstv = ei + NE;

    k_setup<<<(NN * 64 + 255) / 256, 256, 0, stream>>>(
        x, xb, cnt, part, pool_sum, pool_max,
        Wl[0], Wr[0], Wl[1], Wr[1], Wl[2], Wr[2], Bp);
    k_scatter<<<SC_CHUNKS * SC_NB, 256, 0, stream>>>(srcv, dstv, cnt, col);

    // layer 0: raw input xb -> pre-BN b0
    k_layer<0><<<LAYER_BLOCKS, 256, 0, stream>>>(xb, cnt, col, Bp,
                                                 nullptr, nullptr, nullptr, part, b0);
    // layer 1: pre-BN b0 with layer-0 norm folded per-edge -> pre-BN b1
    k_layer<1><<<LAYER_BLOCKS, 256, 0, stream>>>(b0, cnt, col, Bp + 32768,
                                                 part, gma[0], bta[0], part + 16384, b1);
    // layer 2: pre-BN b1 with layer-1 norm folded per-edge -> pre-BN b0
    k_layer<1><<<LAYER_BLOCKS, 256, 0, stream>>>(b1, cnt, col, Bp + 65536,
                                                 part + 16384, gma[1], bta[1], part + 32768, b0);

    k_pool<<<NG * 8, 256, 0, stream>>>(b0, batch, part + 32768, gma[2], bta[2],
                                       pool_sum, pool_max);
    k_head<<<NG, 128, 0, stream>>>(pool_sum, pool_max, batch, gfeats,
                                   W1, bs1, W2, bs2, W3, bs3, (float*)d_out);
}

// Round 14
// 330.083 us; speedup vs baseline: 1.0755x; 1.0755x over previous
//
#include <hip/hip_runtime.h>
#include <stdint.h>

#define NN 50000
#define NE 800000
#define HID 128
#define NG 64
#define BN_EPS 1e-5f
#define SC_NB 8                                  // buckets (== XCD count)
#define SC_BSZ ((NN + SC_NB - 1) / SC_NB)        // 6250 nodes per bucket
#define SC_CHUNK 4096                            // edges per block
#define SC_CHUNKS ((NE + SC_CHUNK - 1) / SC_CHUNK)
#define CAP 96          // fixed CSR row capacity; Poisson(16) P(deg>96) ~ 1e-40
#define LAYER_BLOCKS (NN / 16)                   // 3125 blocks x 16 nodes (exact)
#define NPART 64        // BN-stat partial slots (block & 63); kills atomic contention

typedef __bf16 bf16x8 __attribute__((ext_vector_type(8)));
typedef float floatx4 __attribute__((ext_vector_type(4)));

__device__ __forceinline__ float b2f(unsigned short u) {
    union { unsigned int i; float f; } x; x.i = ((unsigned int)u) << 16; return x.f;
}
__device__ __forceinline__ float blo(unsigned int d) { return __uint_as_float(d << 16); }
__device__ __forceinline__ float bhi(unsigned int d) { return __uint_as_float(d & 0xffff0000u); }
__device__ __forceinline__ unsigned short f2b(float f) {
    union { float f; unsigned int i; } x; x.f = f; unsigned int i = x.i;
    if ((i & 0x7f800000u) == 0x7f800000u) return (unsigned short)(i >> 16); // inf/nan
    return (unsigned short)((i + 0x7fffu + ((i >> 16) & 1u)) >> 16);        // RNE
}
__device__ __forceinline__ unsigned int pack2(float f0, float f1) {
    return (((unsigned int)f2b(f1)) << 16) | f2b(f0);
}
// folded BN scale/shift for column c from the 64-slot partial-sum array
__device__ __forceinline__ float2 bn_pair_part(const float* __restrict__ part,
                                               const float* __restrict__ gamma,
                                               const float* __restrict__ beta, int c) {
    float s = 0.f, sq = 0.f;
#pragma unroll 8
    for (int k = 0; k < NPART; ++k) {
        s += part[k * 256 + c];
        sq += part[k * 256 + 128 + c];
    }
    float mu = s * (1.f / NN);
    float var = sq * (1.f / NN) - mu * mu;
    float sc = gamma[c] * rsqrtf(var + BN_EPS);
    return make_float2(sc, beta[c] - mu * sc);
}
// first index i with batch[i] >= val (batch sorted ascending)
__device__ __forceinline__ int lbound(const int* __restrict__ batch, int val) {
    int lo = 0, hi = NN;
    while (lo < hi) { int mid = (lo + hi) >> 1; if (batch[mid] < val) lo = mid + 1; else hi = mid; }
    return lo;
}

// ---------------- setup (incl. weight prep) ----------------
__global__ void k_setup(const float* __restrict__ x, unsigned short* xb, int* cnt,
                        float* part, float* pool_sum, int* pool_max,
                        const float* __restrict__ Wl0, const float* __restrict__ Wr0,
                        const float* __restrict__ Wl1, const float* __restrict__ Wr1,
                        const float* __restrict__ Wl2, const float* __restrict__ Wr2,
                        unsigned short* Bp) {
    int i = blockIdx.x * 256 + threadIdx.x;
    if (i < NN * 64) {
        float2 v = ((const float2*)x)[i];
        ((unsigned int*)xb)[i] = pack2(v.x, v.y);
    }
    if (i < NN) cnt[i] = 0;
    if (i < 3 * NPART * 256) part[i] = 0.f;
    if (i < NG * HID) { pool_sum[i] = 0.f; pool_max[i] = 0; }
    if (i < 3 * 32768) {
        int layer = i >> 15;
        int r = i & 32767;
        int nt = r >> 12, kk = (r >> 9) & 7, l = (r >> 3) & 63, j = r & 7;
        int k = kk * 32 + (l >> 4) * 8 + j;
        int n = nt * 16 + (l & 15);
        const float* Wl = layer == 0 ? Wl0 : (layer == 1 ? Wl1 : Wl2);
        const float* Wr = layer == 0 ? Wr0 : (layer == 1 ? Wr1 : Wr2);
        Bp[i] = f2b((k < 128) ? Wl[k * 128 + n] : Wr[(k - 128) * 128 + n]);
    }
}

// XCD-bucketized scatter into fixed-capacity CSR (no hist/scan needed).
// blockIdx&7 == bucket == XCD id (round-robin dispatch), so cnt atomics for a
// given node range stay XCD-local — do NOT de-bucketize.
__global__ void k_scatter(const int* __restrict__ src, const int* __restrict__ dst,
                          int* cnt, int* col) {
    int bucket = blockIdx.x & (SC_NB - 1);
    int chunk = blockIdx.x / SC_NB;
    int lo = bucket * SC_BSZ, hi = lo + SC_BSZ;
    int base = chunk * SC_CHUNK;
#pragma unroll
    for (int i = 0; i < SC_CHUNK / 256; ++i) {
        int e = base + i * 256 + threadIdx.x;
        if (e < NE) {
            int d = dst[e];
            if (d >= lo && d < hi) {
                int p = atomicAdd(&cnt[d], 1);
                if (p < CAP) col[d * CAP + p] = src[e];
            }
        }
    }
}

// ---------------- fused layer: gather-agg (LDS) + GEMM + BN partials ---------
// R11-proven structure (43.2us/layer). 16 nodes/block, 3125 blocks; phase 1 =
// wave-cooperative gather (16 lanes/node) unrolled x8 for MLP; self-term row
// load HOISTED above the gather loop so its ~600cy latency hides under the
// gather instead of serializing before the barrier. Phase 2: 8 N-tiles split
// 2-per-wave; A from 8KB XOR-swizzled LDS; B straight from L2. BN stats ->
// part[b&63][256] partials (no 800K-atomic hotspot).
__global__ void __launch_bounds__(256) k_layer(const unsigned short* __restrict__ h,
                                               const int* __restrict__ cnt,
                                               const int* __restrict__ col,
                                               const unsigned short* __restrict__ Bg,
                                               float* __restrict__ part,
                                               unsigned short* __restrict__ out) {
    __shared__ uint4 aggt4[256];   // 4KB agg fragments (swizzled)
    __shared__ uint4 selft4[256];  // 4KB self-term fragments (swizzled)
    int t = threadIdx.x;
    int wid = t >> 6, lane = t & 63;
    const uint4* h4 = (const uint4*)h;  // one row = 16 uint4 (256B)
    // ---- phase 1: gather (16 lanes/node, 4 nodes/wave, 16 nodes/block) ----
    {
        int slot = lane >> 4, sub = lane & 15;
        int nl = wid * 4 + slot;                 // node_local in [0,16)
        int node = blockIdx.x * 16 + nl;         // always < NN (3125*16 == NN)
        int n = cnt[node]; if (n > CAP) n = CAP;
        const int* row = col + (size_t)node * CAP;
        uint4 sv = h4[(size_t)node * 16 + sub];  // self-term: issue EARLY (hoisted)
        float a0 = 0.f, a1 = 0.f, a2 = 0.f, a3 = 0.f, a4 = 0.f, a5 = 0.f, a6 = 0.f, a7 = 0.f;
        int j = 0;
        for (; j + 8 <= n; j += 8) {
            int u0 = row[j], u1 = row[j + 1], u2 = row[j + 2], u3 = row[j + 3];
            int u4 = row[j + 4], u5 = row[j + 5], u6 = row[j + 6], u7 = row[j + 7];
            uint4 v0 = h4[(size_t)u0 * 16 + sub];
            uint4 v1 = h4[(size_t)u1 * 16 + sub];
            uint4 v2 = h4[(size_t)u2 * 16 + sub];
            uint4 v3 = h4[(size_t)u3 * 16 + sub];
            uint4 v4 = h4[(size_t)u4 * 16 + sub];
            uint4 v5 = h4[(size_t)u5 * 16 + sub];
            uint4 v6 = h4[(size_t)u6 * 16 + sub];
            uint4 v7 = h4[(size_t)u7 * 16 + sub];
            a0 += ((blo(v0.x) + blo(v1.x)) + (blo(v2.x) + blo(v3.x))) +
                  ((blo(v4.x) + blo(v5.x)) + (blo(v6.x) + blo(v7.x)));
            a1 += ((bhi(v0.x) + bhi(v1.x)) + (bhi(v2.x) + bhi(v3.x))) +
                  ((bhi(v4.x) + bhi(v5.x)) + (bhi(v6.x) + bhi(v7.x)));
            a2 += ((blo(v0.y) + blo(v1.y)) + (blo(v2.y) + blo(v3.y))) +
                  ((blo(v4.y) + blo(v5.y)) + (blo(v6.y) + blo(v7.y)));
            a3 += ((bhi(v0.y) + bhi(v1.y)) + (bhi(v2.y) + bhi(v3.y))) +
                  ((bhi(v4.y) + bhi(v5.y)) + (bhi(v6.y) + bhi(v7.y)));
            a4 += ((blo(v0.z) + blo(v1.z)) + (blo(v2.z) + blo(v3.z))) +
                  ((blo(v4.z) + blo(v5.z)) + (blo(v6.z) + blo(v7.z)));
            a5 += ((bhi(v0.z) + bhi(v1.z)) + (bhi(v2.z) + bhi(v3.z))) +
                  ((bhi(v4.z) + bhi(v5.z)) + (bhi(v6.z) + bhi(v7.z)));
            a6 += ((blo(v0.w) + blo(v1.w)) + (blo(v2.w) + blo(v3.w))) +
                  ((blo(v4.w) + blo(v5.w)) + (blo(v6.w) + blo(v7.w)));
            a7 += ((bhi(v0.w) + bhi(v1.w)) + (bhi(v2.w) + bhi(v3.w))) +
                  ((bhi(v4.w) + bhi(v5.w)) + (bhi(v6.w) + bhi(v7.w)));
        }
        for (; j + 4 <= n; j += 4) {
            int u0 = row[j], u1 = row[j + 1], u2 = row[j + 2], u3 = row[j + 3];
            uint4 v0 = h4[(size_t)u0 * 16 + sub];
            uint4 v1 = h4[(size_t)u1 * 16 + sub];
            uint4 v2 = h4[(size_t)u2 * 16 + sub];
            uint4 v3 = h4[(size_t)u3 * 16 + sub];
            a0 += (blo(v0.x) + blo(v1.x)) + (blo(v2.x) + blo(v3.x));
            a1 += (bhi(v0.x) + bhi(v1.x)) + (bhi(v2.x) + bhi(v3.x));
            a2 += (blo(v0.y) + blo(v1.y)) + (blo(v2.y) + blo(v3.y));
            a3 += (bhi(v0.y) + bhi(v1.y)) + (bhi(v2.y) + bhi(v3.y));
            a4 += (blo(v0.z) + blo(v1.z)) + (blo(v2.z) + blo(v3.z));
            a5 += (bhi(v0.z) + bhi(v1.z)) + (bhi(v2.z) + bhi(v3.z));
            a6 += (blo(v0.w) + blo(v1.w)) + (blo(v2.w) + blo(v3.w));
            a7 += (bhi(v0.w) + bhi(v1.w)) + (bhi(v2.w) + bhi(v3.w));
        }
        for (; j < n; ++j) {
            int u = row[j];
            uint4 v = h4[(size_t)u * 16 + sub];
            a0 += blo(v.x);  a1 += bhi(v.x);
            a2 += blo(v.y);  a3 += bhi(v.y);
            a4 += blo(v.z);  a5 += bhi(v.z);
            a6 += blo(v.w);  a7 += bhi(v.w);
        }
        float inv = (n > 0) ? 1.f / (float)n : 0.f;
        uint4 o;
        o.x = pack2(a0 * inv, a1 * inv);
        o.y = pack2(a2 * inv, a3 * inv);
        o.z = pack2(a4 * inv, a5 * inv);
        o.w = pack2(a6 * inv, a7 * inv);
        int swz = sub ^ (nl & 7);                // XOR-swizzle 16B chunks
        aggt4[nl * 16 + swz] = o;
        selft4[nl * 16 + swz] = sv;              // self-term row (loaded above)
    }
    __syncthreads();
    // ---- phase 2: MFMA; wave wid handles N-tiles nt = 2*wid, 2*wid+1 ----
    int m = lane & 15, q = lane >> 4;
    int mbase = blockIdx.x * 16;
    const bf16x8* Bv = (const bf16x8*)Bg;
    bf16x8 af[8];
#pragma unroll
    for (int kk = 0; kk < 4; ++kk) {
        int ci = (kk * 4 + q) ^ (m & 7);
        af[kk] = *(const bf16x8*)&aggt4[m * 16 + ci];
        af[4 + kk] = *(const bf16x8*)&selft4[m * 16 + ci];
    }
    floatx4 acc[2];
    acc[0] = (floatx4){0.f, 0.f, 0.f, 0.f};
    acc[1] = (floatx4){0.f, 0.f, 0.f, 0.f};
#pragma unroll
    for (int kk = 0; kk < 8; ++kk) {
#pragma unroll
        for (int ntl = 0; ntl < 2; ++ntl) {
            int nt = wid * 2 + ntl;
            bf16x8 b = Bv[(nt * 8 + kk) * 64 + lane];  // L2-resident broadcast
            acc[ntl] = __builtin_amdgcn_mfma_f32_16x16x32_bf16(af[kk], b, acc[ntl], 0, 0, 0);
        }
    }
    float s8[2] = {0.f, 0.f}, ss8[2] = {0.f, 0.f};
#pragma unroll
    for (int ntl = 0; ntl < 2; ++ntl) {
        int c = (wid * 2 + ntl) * 16 + m;  // C/D: col = lane&15
#pragma unroll
        for (int reg = 0; reg < 4; ++reg) {
            int r = mbase + q * 4 + reg;   // C/D: row = quad*4+reg; always < NN
            float v = acc[ntl][reg];
            out[(size_t)r * 128 + c] = f2b(v);
            s8[ntl] += v;
            ss8[ntl] += v * v;
        }
        s8[ntl] += __shfl_xor(s8[ntl], 16, 64);  s8[ntl] += __shfl_xor(s8[ntl], 32, 64);
        ss8[ntl] += __shfl_xor(ss8[ntl], 16, 64); ss8[ntl] += __shfl_xor(ss8[ntl], 32, 64);
    }
    float* pb = part + (blockIdx.x & (NPART - 1)) * 256;
    if (lane < 16) {
#pragma unroll
        for (int ntl = 0; ntl < 2; ++ntl) {
            int c = (wid * 2 + ntl) * 16 + m;
            atomicAdd(&pb[c], s8[ntl]);
            atomicAdd(&pb[128 + c], ss8[ntl]);
        }
    }
}

// materialize hn = relu(norm(pre)); scale/shift from part reduction (L2-hot)
__global__ void k_norm(const unsigned short* __restrict__ pre,
                       const float* __restrict__ part, const float* __restrict__ gamma,
                       const float* __restrict__ beta, unsigned short* __restrict__ hn) {
    __shared__ float sc[128], sh[128];
    int t = threadIdx.x;
    if (t < 128) {
        float2 p = bn_pair_part(part, gamma, beta, t);
        sc[t] = p.x; sh[t] = p.y;
    }
    __syncthreads();
#pragma unroll
    for (int ii = 0; ii < 4; ++ii) {
        int i = (blockIdx.x * 4 + ii) * 256 + t;  // uint4 index
        if (i < NN * 16) {
            uint4 v = ((const uint4*)pre)[i];
            int cb = (i & 15) * 8;
            uint4 o;
            o.x = pack2(fmaxf(blo(v.x) * sc[cb + 0] + sh[cb + 0], 0.f),
                        fmaxf(bhi(v.x) * sc[cb + 1] + sh[cb + 1], 0.f));
            o.y = pack2(fmaxf(blo(v.y) * sc[cb + 2] + sh[cb + 2], 0.f),
                        fmaxf(bhi(v.y) * sc[cb + 3] + sh[cb + 3], 0.f));
            o.z = pack2(fmaxf(blo(v.z) * sc[cb + 4] + sh[cb + 4], 0.f),
                        fmaxf(bhi(v.z) * sc[cb + 5] + sh[cb + 5], 0.f));
            o.w = pack2(fmaxf(blo(v.w) * sc[cb + 6] + sh[cb + 6], 0.f),
                        fmaxf(bhi(v.w) * sc[cb + 7] + sh[cb + 7], 0.f));
            ((uint4*)hn)[i] = o;
        }
    }
}

// ---------------- pooling (folded norm inline; bounds via binary search) -----
__global__ void k_pool(const unsigned short* __restrict__ h, const int* __restrict__ batch,
                       const float* __restrict__ part,
                       const float* __restrict__ gamma, const float* __restrict__ beta,
                       float* pool_sum, int* pool_max) {
    int g = blockIdx.x >> 3, chunk = blockIdx.x & 7;
    int s = lbound(batch, g), e1 = lbound(batch, g + 1);
    if (s >= e1) return;
    int cnt = e1 - s;
    int per = (cnt + 7) >> 3;
    int r0 = s + chunk * per;
    int r1 = min(r0 + per, e1);
    int c = threadIdx.x & 127, half = threadIdx.x >> 7;
    float2 pr = bn_pair_part(part, gamma, beta, c);
    float sm = 0.f, mx = 0.f;  // post-relu values are >= 0
    for (int r = r0 + half; r < r1; r += 2) {
        float v = fmaxf(b2f(h[(size_t)r * 128 + c]) * pr.x + pr.y, 0.f);
        sm += v;
        mx = fmaxf(mx, v);
    }
    atomicAdd(&pool_sum[g * 128 + c], sm);
    atomicMax(&pool_max[g * 128 + c], __float_as_int(mx));  // valid for >=0 floats
}

__global__ void __launch_bounds__(128) k_head(
    const float* __restrict__ pool_sum, const int* __restrict__ pool_max,
    const int* __restrict__ batch, const float* __restrict__ gfeats,
    const float* __restrict__ W1, const float* __restrict__ bs1,
    const float* __restrict__ W2, const float* __restrict__ bs2,
    const float* __restrict__ W3, const float* __restrict__ bs3,
    float* out) {
    __shared__ float m[288];
    __shared__ float o1[128];
    __shared__ float o2[64];
    int g = blockIdx.x, t = threadIdx.x;
    int cint = lbound(batch, g + 1) - lbound(batch, g);
    float cnt = (float)(cint < 1 ? 1 : cint);
    if (t < 128) {
        m[t] = pool_sum[g * 128 + t] / cnt;
        m[128 + t] = __int_as_float(pool_max[g * 128 + t]);
    }
    if (t < 32) m[256 + t] = gfeats[g * 32 + t];
    __syncthreads();
    float acc = bs1[t];
    for (int k = 0; k < 288; ++k) acc += m[k] * W1[k * 128 + t];
    o1[t] = fmaxf(acc, 0.f);
    __syncthreads();
    if (t < 64) {
        float a2 = bs2[t];
        for (int k = 0; k < 128; ++k) a2 += o1[k] * W2[k * 64 + t];
        o2[t] = fmaxf(a2, 0.f);
    }
    __syncthreads();
    if (t < 64) {
        float p = o2[t] * W3[t];
#pragma unroll
        for (int off = 32; off; off >>= 1) p += __shfl_down(p, off, 64);
        if (t == 0) out[g] = p + bs3[0];
    }
}

// ---------------- launch ----------------
extern "C" void kernel_launch(void* const* d_in, const int* in_sizes, int n_in,
                              void* d_out, int out_size, void* d_ws, size_t ws_size,
                              hipStream_t stream) {
    const float* x = (const float*)d_in[0];
    const int* ei = (const int*)d_in[1];
    const int* batch = (const int*)d_in[2];
    const float* gfeats = (const float*)d_in[3];
    const float *Wl[3], *Wr[3], *gma[3], *bta[3];
    for (int i = 0; i < 3; ++i) {
        Wl[i] = (const float*)d_in[4 + 5 * i];
        // d_in[5+5i] = bl (cancelled by BatchNorm; unused)
        Wr[i] = (const float*)d_in[6 + 5 * i];
        gma[i] = (const float*)d_in[7 + 5 * i];
        bta[i] = (const float*)d_in[8 + 5 * i];
    }
    const float* W1 = (const float*)d_in[19];
    const float* bs1 = (const float*)d_in[20];
    const float* W2 = (const float*)d_in[21];
    const float* bs2 = (const float*)d_in[22];
    const float* W3 = (const float*)d_in[23];
    const float* bs3 = (const float*)d_in[24];

    char* p = (char*)d_ws;
    auto alloc = [&](size_t bytes) -> char* {
        char* r = p;
        p += (bytes + 255) & ~(size_t)255;
        return r;
    };
    int* cnt = (int*)alloc(NN * 4);
    int* col = (int*)alloc((size_t)NN * CAP * 4);
    float* part = (float*)alloc(3 * NPART * 256 * 4);  // BN partial sums
    float* pool_sum = (float*)alloc(NG * HID * 4);
    int* pool_max = (int*)alloc(NG * HID * 4);
    unsigned short* Bp = (unsigned short*)alloc(3 * 32768 * 2);
    unsigned short* xb = (unsigned short*)alloc((size_t)NN * 128 * 2);
    unsigned short* b0 = (unsigned short*)alloc((size_t)NN * 128 * 2);
    unsigned short* b1 = (unsigned short*)alloc((size_t)NN * 128 * 2);
    unsigned short* hn0 = (unsigned short*)alloc((size_t)NN * 128 * 2);

    const int* srcv = ei;
    const int* dstv = ei + NE;

    k_setup<<<(NN * 64 + 255) / 256, 256, 0, stream>>>(
        x, xb, cnt, part, pool_sum, pool_max,
        Wl[0], Wr[0], Wl[1], Wr[1], Wl[2], Wr[2], Bp);
    k_scatter<<<SC_CHUNKS * SC_NB, 256, 0, stream>>>(srcv, dstv, cnt, col);

    // layer 0: input xb (raw) -> pre-BN b0
    k_layer<<<LAYER_BLOCKS, 256, 0, stream>>>(xb, cnt, col, Bp, part, b0);
    k_norm<<<(NN * 16 + 1023) / 1024, 256, 0, stream>>>(b0, part, gma[0], bta[0], hn0);
    // layer 1: input hn0 -> pre-BN b1
    k_layer<<<LAYER_BLOCKS, 256, 0, stream>>>(hn0, cnt, col, Bp + 32768, part + 16384, b1);
    k_norm<<<(NN * 16 + 1023) / 1024, 256, 0, stream>>>(b1, part + 16384, gma[1], bta[1], xb);  // xb = hn1
    // layer 2: input xb (= hn1) -> pre-BN b0 (free after norm0)
    k_layer<<<LAYER_BLOCKS, 256, 0, stream>>>(xb, cnt, col, Bp + 65536, part + 32768, b0);

    k_pool<<<NG * 8, 256, 0, stream>>>(b0, batch, part + 32768, gma[2], bta[2],
                                       pool_sum, pool_max);
    k_head<<<NG, 128, 0, stream>>>(pool_sum, pool_max, batch, gfeats,
                                   W1, bs1, W2, bs2, W3, bs3, (float*)d_out);
}